// Round 5
// baseline (559.463 us; speedup 1.0000x reference)
//
#include <hip/hip_runtime.h>

#define D    768
#define T    16384
#define TQ   8192
#define BINS 1024
#define K1   1536            // conv GEMM K = D*2
#define NKA  (K1 / 32)       // 48 k-blocks (conv operands)
#define NKS  (D / 32)        // 24 k-blocks (score operands)
#define FRAG 1024            // bytes per fragment: 64 lanes x 16 B

#define NFRAG_W  ((D / 16) * NKA)     // 2304 W fragments
#define NFRAG_CB ((BINS / 16) * NKS)  // 1536 codebook fragments
#define NB_PACKB ((NFRAG_W + NFRAG_CB) / 4)   // 960 blocks
#define NB_PACKA (NKA * (TQ / 128))           // 3072 blocks
#define NB_CNORM (BINS / 4)                   // 256 blocks

typedef _Float16 f16;
typedef _Float16 h8 __attribute__((ext_vector_type(8)));
typedef float    f32x4 __attribute__((ext_vector_type(4)));

// Fragment-major layout, all f16 planes:
//   plane[(r16 * NK + kblk) * 64 + lane] is an h8 (16 B);
//   lane l holds row r16*16 + (l&15), k = kblk*32 + 8*(l>>4) + 0..7
// Matches mfma_f32_16x16x32_f16 A/B operand layout (harness-verified r1-r4).

__device__ __forceinline__ void gl_lds16(const void* g, void* l) {
    __builtin_amdgcn_global_load_lds(
        (const __attribute__((address_space(1))) void*)g,
        (__attribute__((address_space(3))) void*)l, 16, 0, 0);
}

// ---------------------------------------------------------------------------
// Fused prep: [0, NB_PACKB)           pack W + codebook into fragment planes
//             [NB_PACKB, +NB_PACKA)   pack ssl batch-0 -> A fragments
//             [.., +NB_CNORM)         cnorm[bin] = ||codebook[bin]||^2
// ---------------------------------------------------------------------------
__global__ __launch_bounds__(256) void prep_kernel(
    const float* __restrict__ ssl, const float* __restrict__ W,
    const float* __restrict__ cb,
    f16* __restrict__ Whi, f16* __restrict__ Wlo,
    f16* __restrict__ CBhi, f16* __restrict__ CBlo,
    f16* __restrict__ Ahi, f16* __restrict__ Alo,
    float* __restrict__ cnorm)
{
    int b = blockIdx.x;
    int wid = threadIdx.x >> 6, lane = threadIdx.x & 63;

    if (b < NB_PACKB) {
        int fid = b * 4 + wid;
        const float* src; f16* hi; f16* lo; int K, nk, fidl;
        if (fid < NFRAG_W) { src = W;  hi = Whi;  lo = Wlo;  K = K1; nk = NKA; fidl = fid; }
        else               { src = cb; hi = CBhi; lo = CBlo; K = D;  nk = NKS; fidl = fid - NFRAG_W; }
        int r16 = fidl / nk, kblk = fidl - r16 * nk;
        int row = r16 * 16 + (lane & 15);
        int k0  = kblk * 32 + 8 * (lane >> 4);
        const float* s = src + (size_t)row * K + k0;
        float4 v0 = *(const float4*)s;
        float4 v1 = *(const float4*)(s + 4);
        float vv[8] = {v0.x, v0.y, v0.z, v0.w, v1.x, v1.y, v1.z, v1.w};
        h8 vh, vl;
        #pragma unroll
        for (int j = 0; j < 8; ++j) {
            f16 h = (f16)vv[j];
            vh[j] = h;
            vl[j] = (f16)((vv[j] - (float)h) * 2048.f);
        }
        size_t off = ((size_t)fidl * 64 + lane) * 8;
        *(h8*)&hi[off] = vh;
        *(h8*)&lo[off] = vl;
    } else if (b < NB_PACKB + NB_PACKA) {
        int idx = b - NB_PACKB;
        int kblk = idx % NKA, yb = idx / NKA;
        int l15 = lane & 15, lk = lane >> 4;
        #pragma unroll
        for (int q = 0; q < 2; ++q) {
            int tblk = yb * 8 + wid * 2 + q;
            int tp = tblk * 16 + l15;
            int i0 = kblk * 16 + 4 * lk;
            float vv[8];
            #pragma unroll
            for (int ii = 0; ii < 4; ++ii) {
                float2 v = *(const float2*)&ssl[(size_t)(i0 + ii) * T + 2 * tp];
                vv[2 * ii]     = v.x;
                vv[2 * ii + 1] = v.y;
            }
            h8 vh, vl;
            #pragma unroll
            for (int j = 0; j < 8; ++j) {
                f16 h = (f16)vv[j];
                vh[j] = h;
                vl[j] = (f16)((vv[j] - (float)h) * 2048.f);
            }
            size_t off = ((size_t)(tblk * NKA + kblk) * 64 + lane) * 8;
            *(h8*)&Ahi[off] = vh;
            *(h8*)&Alo[off] = vl;
        }
    } else {
        int bin = (b - NB_PACKB - NB_PACKA) * 4 + wid;
        const float* row = cb + (size_t)bin * D;
        float s = 0.f;
        for (int k = lane; k < D; k += 64) { float v = row[k]; s += v * v; }
        #pragma unroll
        for (int off = 32; off > 0; off >>= 1) s += __shfl_down(s, off);
        if (lane == 0) cnorm[bin] = s;
    }
}

// ---- shared GEMM building blocks (hybrid: A in regs, B via global_load_lds)
// Per wave: 4 glds of its 4 frags fg = wid*4+j of [Bh frags 0..7 | Bl 8..15].
#define STAGE_B(BH, BL, bufbase, NK, kb)                                      \
    {                                                                         \
        _Pragma("unroll")                                                     \
        for (int j = 0; j < 4; ++j) {                                         \
            int fg = wid * 4 + j;                                             \
            const char* gp = (fg < 8 ? (const char*)(BH) : (const char*)(BL)) \
                + (((size_t)(nb16 + (fg & 7)) * (NK) + (kb)) << 10)           \
                + lane * 16;                                                  \
            gl_lds16(gp, (bufbase) + fg * 1024);                              \
        }                                                                     \
    }

#define LOAD_A(AHP, ALP, AH, AL, NK, kb)                                      \
    {                                                                         \
        _Pragma("unroll")                                                     \
        for (int mf = 0; mf < 4; ++mf) {                                      \
            size_t fo = (((size_t)(mb16 + wm * 4 + mf) * (NK) + (kb)) << 10)  \
                + lane * 16;                                                  \
            AH[mf] = *(const h8*)((const char*)(AHP) + fo);                   \
            AL[mf] = *(const h8*)((const char*)(ALP) + fo);                   \
        }                                                                     \
    }

#define GEMM_COMPUTE(bufbase, AH, AL)                                         \
    {                                                                         \
        const char* bb = (bufbase);                                           \
        _Pragma("unroll")                                                     \
        for (int nf = 0; nf < 4; ++nf) {                                      \
            int fo = (wn * 4 + nf) * 1024 + lane * 16;                        \
            h8 bh = *(const h8*)(bb + fo);                                    \
            h8 bl = *(const h8*)(bb + 8192 + fo);                             \
            _Pragma("unroll")                                                 \
            for (int mf = 0; mf < 4; ++mf) {                                  \
                acc [mf][nf] = __builtin_amdgcn_mfma_f32_16x16x32_f16(AH[mf], bh, acc [mf][nf], 0, 0, 0); \
                acc2[mf][nf] = __builtin_amdgcn_mfma_f32_16x16x32_f16(AH[mf], bl, acc2[mf][nf], 0, 0, 0); \
                acc2[mf][nf] = __builtin_amdgcn_mfma_f32_16x16x32_f16(AL[mf], bh, acc2[mf][nf], 0, 0, 0); \
            }                                                                 \
        }                                                                     \
    }

// ---------------------------------------------------------------------------
// Conv as split-fp16 MFMA GEMM, hybrid staging: A fragments global->VGPR
// (prefetched 1 K-step ahead, manual 2-step unroll), W via global_load_lds
// double-buffer (2 x 16 KB). One barrier per K-step. Cross terms in
// persistent acc2, folded at epilogue. XCD-chunked swizzle (384 %8==0).
// Epilogue: 4-slab LDS transpose -> X written fragment-major for score.
// ---------------------------------------------------------------------------
__global__ __launch_bounds__(256, 2) void conv_mfma_kernel(
    const f16* __restrict__ Ah, const f16* __restrict__ Al,   // [TQ/16][NKA] frags
    const f16* __restrict__ Bh, const f16* __restrict__ Bl,   // [D/16][NKA] frags
    const float* __restrict__ bias,
    f16* __restrict__ Xhi, f16* __restrict__ Xlo)             // [TQ/16][NKS] frags
{
    __shared__ __align__(16) char smem[32768];   // 2 x 16 KB B buffers
    int tid = threadIdx.x, lane = tid & 63, wid = tid >> 6;
    int wm = wid >> 1, wn = wid & 1;
    int l15 = lane & 15, lk = lane >> 4;

    int orig = blockIdx.y * 6 + blockIdx.x;          // grid (6, 64)
    int swz  = (orig & 7) * 48 + (orig >> 3);
    int bx = swz % 6, by = swz / 6;
    int mb = by * 128, nb = bx * 128;
    int mb16 = mb >> 4, nb16 = nb >> 4;

    const f32x4 zero4 = {0.f, 0.f, 0.f, 0.f};
    f32x4 acc[4][4], acc2[4][4];
    #pragma unroll
    for (int i = 0; i < 4; ++i)
        #pragma unroll
        for (int j = 0; j < 4; ++j) { acc[i][j] = zero4; acc2[i][j] = zero4; }

    h8 a0h[4], a0l[4], a1h[4], a1l[4];
    LOAD_A(Ah, Al, a0h, a0l, NKA, 0);
    STAGE_B(Bh, Bl, smem, NKA, 0);
    __syncthreads();

    for (int kb = 0; kb < NKA; kb += 2) {
        // step A: compute kb from buf0; prefetch kb+1 (buf1 + regs)
        STAGE_B(Bh, Bl, smem + 16384, NKA, kb + 1);
        LOAD_A(Ah, Al, a1h, a1l, NKA, kb + 1);
        GEMM_COMPUTE(smem, a0h, a0l);
        __syncthreads();
        // step B: compute kb+1 from buf1; prefetch kb+2 (buf0 + regs)
        if (kb + 2 < NKA) {
            STAGE_B(Bh, Bl, smem, NKA, kb + 2);
            LOAD_A(Ah, Al, a0h, a0l, NKA, kb + 2);
        }
        GEMM_COMPUTE(smem + 16384, a1h, a1l);
        __syncthreads();
    }

    // epilogue: x = acc + acc2/2048 + bias; LDS transpose in 4 slabs of
    // 32 rows (32x132 f32 = 16.9 KB, reuses smem) -> fragment-major X.
    float* sb = (float*)smem;
    float bv[4];
    #pragma unroll
    for (int nf = 0; nf < 4; ++nf) bv[nf] = bias[nb + wn * 64 + nf * 16 + l15];
    #pragma unroll
    for (int s = 0; s < 4; ++s) {
        __syncthreads();
        if (wm == (s >> 1)) {
            #pragma unroll
            for (int mh = 0; mh < 2; ++mh) {
                int mf = (s & 1) * 2 + mh;
                int srow = mh * 16 + lk * 4;
                #pragma unroll
                for (int nf = 0; nf < 4; ++nf) {
                    int scol = wn * 64 + nf * 16 + l15;
                    #pragma unroll
                    for (int r = 0; r < 4; ++r)
                        sb[(srow + r) * 132 + scol] =
                            acc[mf][nf][r] + acc2[mf][nf][r] * 4.8828125e-4f + bv[nf];
                }
            }
        }
        __syncthreads();
        #pragma unroll
        for (int h = 0; h < 2; ++h) {
            int f = wid * 2 + h;          // 0..7: tl = f&1, dbl = f>>1
            int tl = f & 1, dbl = f >> 1;
            int srow = tl * 16 + l15;
            int sd   = dbl * 32 + 8 * lk;
            float vv[8];
            #pragma unroll
            for (int j = 0; j < 8; ++j) vv[j] = sb[srow * 132 + sd + j];
            h8 vh, vl;
            #pragma unroll
            for (int j = 0; j < 8; ++j) {
                f16 hh = (f16)vv[j];
                vh[j] = hh;
                vl[j] = (f16)((vv[j] - (float)hh) * 2048.f);
            }
            int tblk_g = mb16 + s * 2 + tl;
            int dblk_g = (nb >> 5) + dbl;
            size_t off = ((size_t)(tblk_g * NKS + dblk_g) * 64 + lane) * 8;
            *(h8*)&Xhi[off] = vh;
            *(h8*)&Xlo[off] = vl;
        }
    }
}

// ---------------------------------------------------------------------------
// Score: split-fp16 MFMA dot, hybrid staging (X->regs, CB via glds dbuf),
// XCD swizzle (512 %8==0), fused s = cnorm - 2*dot + per-row partial argmin.
// ---------------------------------------------------------------------------
__global__ __launch_bounds__(256, 2) void score_mfma_kernel(
    const f16* __restrict__ Ah, const f16* __restrict__ Al,   // X frags [TQ/16][NKS]
    const f16* __restrict__ Bh, const f16* __restrict__ Bl,   // CB frags [BINS/16][NKS]
    const float* __restrict__ cnorm,
    float* __restrict__ pval, int* __restrict__ pidx)         // [TQ][16]
{
    __shared__ __align__(16) char smem[32768];
    int tid = threadIdx.x, lane = tid & 63, wid = tid >> 6;
    int wm = wid >> 1, wn = wid & 1;
    int l15 = lane & 15, lk = lane >> 4;

    int orig = blockIdx.y * 8 + blockIdx.x;          // grid (8, 64)
    int swz  = (orig & 7) * 64 + (orig >> 3);
    int bx = swz & 7, by = swz >> 3;
    int mb = by * 128, nb = bx * 128;
    int mb16 = mb >> 4, nb16 = nb >> 4;

    const f32x4 zero4 = {0.f, 0.f, 0.f, 0.f};
    f32x4 acc[4][4], acc2[4][4];
    #pragma unroll
    for (int i = 0; i < 4; ++i)
        #pragma unroll
        for (int j = 0; j < 4; ++j) { acc[i][j] = zero4; acc2[i][j] = zero4; }

    h8 a0h[4], a0l[4], a1h[4], a1l[4];
    LOAD_A(Ah, Al, a0h, a0l, NKS, 0);
    STAGE_B(Bh, Bl, smem, NKS, 0);
    __syncthreads();

    for (int kb = 0; kb < NKS; kb += 2) {
        STAGE_B(Bh, Bl, smem + 16384, NKS, kb + 1);
        LOAD_A(Ah, Al, a1h, a1l, NKS, kb + 1);
        GEMM_COMPUTE(smem, a0h, a0l);
        __syncthreads();
        if (kb + 2 < NKS) {
            STAGE_B(Bh, Bl, smem, NKS, kb + 2);
            LOAD_A(Ah, Al, a0h, a0l, NKS, kb + 2);
        }
        GEMM_COMPUTE(smem + 16384, a1h, a1l);
        __syncthreads();
    }

    // epilogue: s = cnorm[col] - 2*(acc + acc2/2048); argmin over 64 cols
    float cn[4];
    #pragma unroll
    for (int nf = 0; nf < 4; ++nf) cn[nf] = cnorm[nb + wn * 64 + nf * 16 + l15];
    int slice = bx * 2 + wn;                  // 16 ascending 64-bin slices
    #pragma unroll
    for (int mf = 0; mf < 4; ++mf) {
        #pragma unroll
        for (int r = 0; r < 4; ++r) {
            float v = 3.4e38f; int ix = 0;
            #pragma unroll
            for (int nf = 0; nf < 4; ++nf) {  // cols ascend: ties -> lowest
                float dot = acc[mf][nf][r] + acc2[mf][nf][r] * 4.8828125e-4f;
                float sc = cn[nf] - 2.f * dot;
                int col = nb + wn * 64 + nf * 16 + l15;
                if (sc < v) { v = sc; ix = col; }
            }
            #pragma unroll
            for (int off = 8; off > 0; off >>= 1) {
                float ov = __shfl_xor(v, off);
                int   oi = __shfl_xor(ix, off);
                if (ov < v || (ov == v && oi < ix)) { v = ov; ix = oi; }
            }
            if (l15 == 0) {
                int row = mb + wm * 64 + mf * 16 + lk * 4 + r;
                pval[row * 16 + slice] = v;
                pidx[row * 16 + slice] = ix;
            }
        }
    }
}

// ---------------------------------------------------------------------------
// Final reduce over 16 ascending bin-slices (strict < keeps lowest index).
// ---------------------------------------------------------------------------
__global__ __launch_bounds__(256) void argmin_final_kernel(
    const float* __restrict__ pval, const int* __restrict__ pidx,
    int* __restrict__ out)
{
    int r = blockIdx.x * 256 + threadIdx.x;
    float best = 3.4e38f; int bi = 0;
    #pragma unroll
    for (int s = 0; s < 16; ++s) {
        float v = pval[r * 16 + s];
        if (v < best) { best = v; bi = pidx[r * 16 + s]; }
    }
    out[r] = bi;
}

extern "C" void kernel_launch(void* const* d_in, const int* in_sizes, int n_in,
                              void* d_out, int out_size, void* d_ws, size_t ws_size,
                              hipStream_t stream) {
    const float* ssl = (const float*)d_in[0];  // [8, 768, 16384]
    const float* W   = (const float*)d_in[1];  // [768][1536], k = 2i+s
    const float* bia = (const float*)d_in[2];  // [768]
    const float* cb  = (const float*)d_in[3];  // [1024, 768]
    int* out = (int*)d_out;                    // [8192] int32 codes

    char* p = (char*)d_ws;
    float* cnorm = (float*)p;  p += 4096;
    f16* Whi  = (f16*)p;  p += (size_t)D * K1 * 2;      // fragment-major planes
    f16* Wlo  = (f16*)p;  p += (size_t)D * K1 * 2;
    f16* CBhi = (f16*)p;  p += (size_t)BINS * D * 2;
    f16* CBlo = (f16*)p;  p += (size_t)BINS * D * 2;
    f16* Ahi  = (f16*)p;  p += (size_t)TQ * K1 * 2;
    f16* Alo  = (f16*)p;  p += (size_t)TQ * K1 * 2;
    f16* Xhi  = (f16*)p;  p += (size_t)TQ * D * 2;
    f16* Xlo  = (f16*)p;  p += (size_t)TQ * D * 2;
    float* pval = (float*)p;  p += (size_t)TQ * 16 * 4;
    int*   pidx = (int*)p;    p += (size_t)TQ * 16 * 4;
    // total ~84.5 MB

    prep_kernel<<<NB_PACKB + NB_PACKA + NB_CNORM, 256, 0, stream>>>(
        ssl, W, cb, Whi, Wlo, CBhi, CBlo, Ahi, Alo, cnorm);
    conv_mfma_kernel<<<dim3(D / 128, TQ / 128), 256, 0, stream>>>(
        Ahi, Alo, Whi, Wlo, bia, Xhi, Xlo);
    score_mfma_kernel<<<dim3(BINS / 128, TQ / 128), 256, 0, stream>>>(
        Xhi, Xlo, CBhi, CBlo, cnorm, pval, pidx);
    argmin_final_kernel<<<TQ / 256, 256, 0, stream>>>(pval, pidx, out);
}